// Round 4
// baseline (2425.337 us; speedup 1.0000x reference)
//
#include <hip/hip_runtime.h>
#include <hip/hip_bf16.h>
#include <math.h>

typedef __bf16 bf16;
typedef __attribute__((ext_vector_type(8))) __bf16 bf16x8;
typedef __attribute__((ext_vector_type(4))) __bf16 bf16x4;
typedef __attribute__((ext_vector_type(4))) float f32x4;

// ---------------- constants ----------------
constexpr int cB = 16, cC = 3, cH = 64, cW = 672;
constexpr int cP = 16, cE = 768, cHEADS = 12, cL = 12;
constexpr int cMLP = 3072, cOUT = 2048;
constexpr int cPH = 4, cPW = 42, cNPAT = 168, cSEQ = 169;
constexpr int cN = cB * cSEQ;          // 2704 packed rows
constexpr int cMp = 2816;              // padded to 22*128 (= 44*64)
constexpr int cDH = 64;
constexpr int NJT = 2, KT = 96;        // 2 key tiles of 96 (keys padded 169->192)

enum { EPI_F32 = 0, EPI_RES = 1, EPI_GELU_BF16 = 2, EPI_BF16 = 3 };

// layer weight block: in_w 1769472 + out_w 589824 + mlp_w1 2359296 + mlp_w2 2359296
constexpr int cWL = 7077888;           // bf16 elems per layer
constexpr size_t cWallBase = 56229888; // byte offset of weight region in ws
constexpr size_t cWsNeedBig = cWallBase + (size_t)cL * cWL * 2; // 226,099,200 B

// ---------------- async global->LDS 16B per lane ----------------
// LDS side is wave-uniform base + lane*16 (HW-added); global side is per-lane gather.
__device__ __forceinline__ void async16(const bf16* g, bf16* l) {
    __builtin_amdgcn_global_load_lds(
        (__attribute__((address_space(1))) void*)(void*)g,
        (__attribute__((address_space(3))) void*)(void*)l,
        16, 0, 0);
}

// bijective XCD-chunk swizzle (m204): consecutive HW block ids round-robin XCDs;
// remap so each XCD owns a contiguous chunk of the linear grid -> A-panel L2 reuse.
__device__ __forceinline__ int xcd_swz(int orig, int nwg) {
    int q = nwg >> 3, r = nwg & 7;
    int xcd = orig & 7, idx = orig >> 3;
    return (xcd < r ? xcd * (q + 1) : r * (q + 1) + (xcd - r) * q) + idx;
}

// ---------------- patchify: pixels -> bf16 patch matrix [2688, 768] ----------------
__global__ __launch_bounds__(256) void patchify_kernel(
    const float* __restrict__ px, bf16* __restrict__ Ap)
{
    int idx = blockIdx.x * 256 + threadIdx.x;            // over 2688*768
    if (idx >= cB * cNPAT * cE) return;
    int gp = idx / cE, e = idx - gp * cE;
    int b = gp / cNPAT, p = gp - b * cNPAT;
    int ph = p / cPW, pw = p - ph * cPW;
    int c = e >> 8, r = (e >> 4) & 15, col = e & 15;
    float v = px[(((size_t)b * cC + c) * cH + (ph * cP + r)) * cW + pw * cP + col];
    Ap[idx] = (bf16)v;
}

// ---------------- assemble: cls + pe + pos -> x fp32 [2704, 768] ----------------
__global__ __launch_bounds__(256) void assemble_kernel(
    const float* __restrict__ pe, const float* __restrict__ row_emb,
    const float* __restrict__ col_emb, const float* __restrict__ cls,
    float* __restrict__ x)
{
    int idx = blockIdx.x * 256 + threadIdx.x;            // over 2704*768
    if (idx >= cN * cE) return;
    int row = idx / cE, e = idx - row * cE;
    int b = row / cSEQ, s = row - b * cSEQ;
    float v;
    if (s == 0) {
        v = cls[e];
    } else {
        int p = s - 1, ph = p / cPW, pw = p - ph * cPW;
        float pos = (e < 384) ? row_emb[ph * 384 + e] : col_emb[pw * 384 + e - 384];
        v = pe[((size_t)b * cNPAT + p) * cE + e] + pos;
    }
    x[idx] = v;
}

// ---------------- fp32 -> bf16 convert (x4 vectorized) ----------------
__global__ __launch_bounds__(256) void f2b_kernel(
    const float* __restrict__ in, bf16* __restrict__ out, int n4)
{
    int i = blockIdx.x * 256 + threadIdx.x;
    if (i >= n4) return;
    f32x4 v = ((const f32x4*)in)[i];
    bf16x4 r;
    r[0] = (bf16)v[0]; r[1] = (bf16)v[1]; r[2] = (bf16)v[2]; r[3] = (bf16)v[3];
    ((bf16x4*)out)[i] = r;
}

// ---------------- batched layer-weight conversion: 4 segments -> wbuf ----------------
// seg sizes (f32x4 units): in_w 442368, out_w 147456, mlp_w1 589824, mlp_w2 589824
__global__ __launch_bounds__(256) void conv4_kernel(
    const float* __restrict__ s0, const float* __restrict__ s1,
    const float* __restrict__ s2, const float* __restrict__ s3,
    bf16* __restrict__ dst)
{
    int i = blockIdx.x * 256 + threadIdx.x;
    if (i >= 1769472) return;
    const float* src; size_t off;
    if (i < 442368)       { src = s0 + (size_t)i * 4;             off = (size_t)i * 4; }
    else if (i < 589824)  { int j = i - 442368;  src = s1 + (size_t)j * 4; off = 1769472 + (size_t)j * 4; }
    else if (i < 1179648) { int j = i - 589824;  src = s2 + (size_t)j * 4; off = 2359296 + (size_t)j * 4; }
    else                  { int j = i - 1179648; src = s3 + (size_t)j * 4; off = 4718592 + (size_t)j * 4; }
    f32x4 v = *(const f32x4*)src;
    bf16x4 r;
    r[0] = (bf16)v[0]; r[1] = (bf16)v[1]; r[2] = (bf16)v[2]; r[3] = (bf16)v[3];
    *(bf16x4*)(dst + off) = r;
}

// ---------------- ALL-layer weight conversion (big-ws mode): one launch ----------------
__global__ __launch_bounds__(256) void conv4_all_kernel(
    const float* __restrict__ in_w, const float* __restrict__ out_w,
    const float* __restrict__ m1, const float* __restrict__ m2,
    bf16* __restrict__ dst)
{
    int i = blockIdx.x * 256 + threadIdx.x;     // over 12*1769472 f32x4 units
    if (i >= cL * 1769472) return;
    int l = i / 1769472, j = i - l * 1769472;
    const float* src; size_t off;
    if (j < 442368)       { src = in_w  + ((size_t)l * 442368 + j) * 4;           off = (size_t)j * 4; }
    else if (j < 589824)  { int k = j - 442368;  src = out_w + ((size_t)l * 147456 + k) * 4; off = 1769472 + (size_t)k * 4; }
    else if (j < 1179648) { int k = j - 589824;  src = m1 + ((size_t)l * 589824 + k) * 4;    off = 2359296 + (size_t)k * 4; }
    else                  { int k = j - 1179648; src = m2 + ((size_t)l * 589824 + k) * 4;    off = 4718592 + (size_t)k * 4; }
    f32x4 v = *(const f32x4*)src;
    bf16x4 r;
    r[0] = (bf16)v[0]; r[1] = (bf16)v[1]; r[2] = (bf16)v[2]; r[3] = (bf16)v[3];
    *(bf16x4*)(dst + (size_t)l * cWL + off) = r;
}

// ---------------- layernorm over D cols; out bf16 or fp32 ----------------
__global__ __launch_bounds__(256) void ln_kernel(
    const float* __restrict__ x, const float* __restrict__ g,
    const float* __restrict__ bta, bf16* __restrict__ outB,
    float* __restrict__ outF, int D)
{
    const int row = blockIdx.x;
    const float* xr = x + (size_t)row * D;
    float s = 0.f, s2 = 0.f;
    for (int d = threadIdx.x; d < D; d += 256) { float v = xr[d]; s += v; s2 += v * v; }
    #pragma unroll
    for (int off = 32; off > 0; off >>= 1) {
        s  += __shfl_down(s, off);
        s2 += __shfl_down(s2, off);
    }
    __shared__ float rs[4], rs2[4];
    if ((threadIdx.x & 63) == 0) { rs[threadIdx.x >> 6] = s; rs2[threadIdx.x >> 6] = s2; }
    __syncthreads();
    s = rs[0] + rs[1] + rs[2] + rs[3];
    s2 = rs2[0] + rs2[1] + rs2[2] + rs2[3];
    const float mean = s / D;
    const float rstd = rsqrtf(s2 / D - mean * mean + 1e-5f);
    for (int d = threadIdx.x; d < D; d += 256) {
        float v = (xr[d] - mean) * rstd * g[d] + bta[d];
        if (outB) outB[(size_t)row * D + d] = (bf16)v;
        else      outF[(size_t)row * D + d] = v;
    }
}

// ---------------- bf16 MFMA GEMM, 64x64 tile, BK=64 (N=768-class shapes) ----------
// 5 blocks/CU, grid 528 for N=768: occupancy-optimized; MFMA:ds_read = 1:1.
__global__ __launch_bounds__(256, 5) void gemm_sq64_kernel(
    const bf16* __restrict__ A, const bf16* __restrict__ Bw,
    const float* __restrict__ bias, const float* __restrict__ res,
    float* __restrict__ outF, bf16* __restrict__ outB,
    int M, int N, int K, int epi)
{
    __shared__ bf16 sA[2 * 64 * 64];     // 16 KB
    __shared__ bf16 sB[2 * 64 * 64];     // 16 KB

    const int tid  = threadIdx.x;
    const int lane = tid & 63;
    const int wave = tid >> 6;

    const int nwg  = gridDim.x * gridDim.y;
    const int swz  = xcd_swz(blockIdx.y * gridDim.x + blockIdx.x, nwg);
    const int bm = (swz / gridDim.x) * 64;
    const int bn = (swz % gridDim.x) * 64;
    const int wm = (wave & 1) * 32;      // 2x2 wave grid, wave tile 32x32
    const int wn = (wave >> 1) * 32;

    const int r_in = lane >> 3;                    // 0..7
    const int swz_col = ((lane & 7) ^ r_in) * 8;   // global elem offset of this lane's chunk

    const int m_lo = lane & 15;
    const int quad = lane >> 4;

    f32x4 acc[2][2];
    #pragma unroll
    for (int i = 0; i < 2; ++i)
        #pragma unroll
        for (int j = 0; j < 2; ++j) {
            f32x4 z = {0.f, 0.f, 0.f, 0.f};
            acc[i][j] = z;
        }

    const int nk = K >> 6;

    auto stage = [&](int kt, int buf) {
        const int k0 = kt << 6;
        const bf16* gA = A  + (size_t)(bm + wave * 16 + r_in) * K + k0 + swz_col;
        const bf16* gB = Bw + (size_t)(bn + wave * 16 + r_in) * K + k0 + swz_col;
        bf16* lA = sA + buf * 4096 + (wave * 16) * 64;
        bf16* lB = sB + buf * 4096 + (wave * 16) * 64;
        #pragma unroll
        for (int d = 0; d < 2; ++d) {
            async16(gA + (size_t)(d * 8) * K, lA + d * 512);
            async16(gB + (size_t)(d * 8) * K, lB + d * 512);
        }
    };

    stage(0, 0);

    for (int kt = 0; kt < nk; ++kt) {
        __syncthreads();
        if (kt + 1 < nk) stage(kt + 1, (kt + 1) & 1);

        const bf16* bufA = sA + (kt & 1) * 4096;
        const bf16* bufB = sB + (kt & 1) * 4096;

        bf16x8 af[2][2], bfr[2][2];
        #pragma unroll
        for (int j = 0; j < 2; ++j)
            #pragma unroll
            for (int i = 0; i < 2; ++i) {
                const int c = ((quad + j * 4) ^ (m_lo & 7)) * 8;   // swizzled chunk
                af[j][i]  = *(const bf16x8*)(bufA + (wm + i * 16 + m_lo) * 64 + c);
                bfr[j][i] = *(const bf16x8*)(bufB + (wn + i * 16 + m_lo) * 64 + c);
            }
        #pragma unroll
        for (int j = 0; j < 2; ++j)
            #pragma unroll
            for (int mi = 0; mi < 2; ++mi)
                #pragma unroll
                for (int ni = 0; ni < 2; ++ni)
                    acc[mi][ni] = __builtin_amdgcn_mfma_f32_16x16x32_bf16(
                        af[j][mi], bfr[j][ni], acc[mi][ni], 0, 0, 0);
    }

    #pragma unroll
    for (int mi = 0; mi < 2; ++mi) {
        #pragma unroll
        for (int ni = 0; ni < 2; ++ni) {
            #pragma unroll
            for (int r = 0; r < 4; ++r) {
                int row = bm + wm + mi * 16 + quad * 4 + r;
                int col = bn + wn + ni * 16 + m_lo;
                float v = acc[mi][ni][r] + bias[col];
                if (epi == EPI_RES) {
                    v += res[(size_t)row * N + col];
                    outF[(size_t)row * N + col] = v;
                } else if (epi == EPI_GELU_BF16) {
                    v = v * 0.5f * (1.0f + erff(v * 0.70710678118f));
                    outB[(size_t)row * N + col] = (bf16)v;
                } else if (epi == EPI_BF16) {
                    outB[(size_t)row * N + col] = (bf16)v;
                } else {
                    outF[(size_t)row * N + col] = v;
                }
            }
        }
    }
}

// ---------------- bf16 MFMA GEMM, 128x128 tile, BK=32 (large-N shapes) ----------
// Round-4 rationale: the 64^2 tile is capped ~300 TF by its 1:1 MFMA:ds_read ratio
// (8 MFMA vs 8 ds_read_b128 per wave-step). This kernel: wave tile 64x64, BK=32 ->
// 16 MFMA vs 8 ds_read = 2:1, LDS only 32 KB. launch_bounds(256,3): ~150 VGPR fits
// without spill; 3 blocks/CU. Grids 264-528 keep every CU fed (qkv 396, mlp1 528).
// LDS rows are 32 elems = 4 chunks of 16 B. Swizzle: phys chunk p of row r holds
// global chunk g = (p - (r>>1)) & 3 -> frag reads (16 lanes, consecutive rows, same
// global chunk) land 2-way bank aliasing (free, m136). DMA dest stays linear;
// source is pre-swizzled per lane (both-sides-or-neither rule, m104/m231).
__global__ __launch_bounds__(256, 3) void gemm_bk32_kernel(
    const bf16* __restrict__ A, const bf16* __restrict__ Bw,
    const float* __restrict__ bias, const float* __restrict__ res,
    float* __restrict__ outF, bf16* __restrict__ outB,
    int M, int N, int K, int epi)
{
    __shared__ bf16 sA[2 * 128 * 32];    // 16 KB
    __shared__ bf16 sB[2 * 128 * 32];    // 16 KB

    const int tid  = threadIdx.x;
    const int lane = tid & 63;
    const int wave = tid >> 6;

    const int nwg  = gridDim.x * gridDim.y;
    const int swz  = xcd_swz(blockIdx.y * gridDim.x + blockIdx.x, nwg);
    const int bm = (swz / gridDim.x) * 128;
    const int bn = (swz % gridDim.x) * 128;
    const int wm = (wave & 1) * 64;      // 2x2 wave grid, wave tile 64x64
    const int wn = (wave >> 1) * 64;

    const int m_lo = lane & 15;
    const int quad = lane >> 4;

    // staging geometry: per matrix a wave covers tile rows [wave*32, wave*32+32),
    // 2 DMAs of 16 rows. lane l -> row (l>>2), phys chunk l&3, global chunk
    // g = ((l&3) - (row>>1)) & 3.
    const int r_sub = lane >> 2;         // 0..15

    f32x4 acc[4][4];
    #pragma unroll
    for (int i = 0; i < 4; ++i)
        #pragma unroll
        for (int j = 0; j < 4; ++j) {
            f32x4 z = {0.f, 0.f, 0.f, 0.f};
            acc[i][j] = z;
        }

    const int nk = K >> 5;

    auto stage = [&](int kt, int buf) {
        const int k0 = kt << 5;
        #pragma unroll
        for (int d = 0; d < 2; ++d) {
            const int rloc = wave * 32 + d * 16 + r_sub;            // tile-local row
            const int g = ((lane & 3) - (rloc >> 1)) & 3;           // global chunk for this slot
            async16(A  + (size_t)(bm + rloc) * K + k0 + g * 8,
                    sA + buf * 4096 + (wave * 32 + d * 16) * 32);
            async16(Bw + (size_t)(bn + rloc) * K + k0 + g * 8,
                    sB + buf * 4096 + (wave * 32 + d * 16) * 32);
        }
    };

    stage(0, 0);

    for (int kt = 0; kt < nk; ++kt) {
        __syncthreads();                 // drains vmcnt(0): tile kt landed
        if (kt + 1 < nk) stage(kt + 1, (kt + 1) & 1);

        const bf16* bufA = sA + (kt & 1) * 4096;
        const bf16* bufB = sB + (kt & 1) * 4096;

        bf16x8 af[4], bfr[4];
        #pragma unroll
        for (int i = 0; i < 4; ++i) {
            const int Ra = wm + i * 16 + m_lo;
            const int pa = (quad + (Ra >> 1)) & 3;
            af[i] = *(const bf16x8*)(bufA + Ra * 32 + pa * 8);
            const int Rb = wn + i * 16 + m_lo;
            const int pb = (quad + (Rb >> 1)) & 3;
            bfr[i] = *(const bf16x8*)(bufB + Rb * 32 + pb * 8);
        }
        #pragma unroll
        for (int mi = 0; mi < 4; ++mi)
            #pragma unroll
            for (int ni = 0; ni < 4; ++ni)
                acc[mi][ni] = __builtin_amdgcn_mfma_f32_16x16x32_bf16(
                    af[mi], bfr[ni], acc[mi][ni], 0, 0, 0);
    }

    // epilogue: C/D layout col=lane&15, row=quad*4+r  (verified m89/m91)
    #pragma unroll
    for (int mi = 0; mi < 4; ++mi) {
        #pragma unroll
        for (int ni = 0; ni < 4; ++ni) {
            #pragma unroll
            for (int r = 0; r < 4; ++r) {
                int row = bm + wm + mi * 16 + quad * 4 + r;
                int col = bn + wn + ni * 16 + m_lo;
                float v = acc[mi][ni][r] + bias[col];
                if (epi == EPI_RES) {
                    v += res[(size_t)row * N + col];
                    outF[(size_t)row * N + col] = v;
                } else if (epi == EPI_GELU_BF16) {
                    v = v * 0.5f * (1.0f + erff(v * 0.70710678118f));
                    outB[(size_t)row * N + col] = (bf16)v;
                } else if (epi == EPI_BF16) {
                    outB[(size_t)row * N + col] = (bf16)v;
                } else {
                    outF[(size_t)row * N + col] = v;
                }
            }
        }
    }
}

// ---------------- MFMA attention: block per (head, image, key-half) ----------------
__global__ __launch_bounds__(384) void attn_mfma_kernel(
    const bf16* __restrict__ qkv, bf16* __restrict__ op, float* __restrict__ ml)
{
    __shared__ bf16 sK[KT * cDH];          // 12 KB, xor-swizzled rows
    __shared__ bf16 sVT[cDH * 104];        // 13 KB, V^T, padded stride 104
    __shared__ bf16 sP[6 * 32 * 104];      // 39 KB, per-wave P tiles

    const int h = blockIdx.x, b = blockIdx.y, kt = blockIdx.z;
    const int tid  = threadIdx.x;
    const int lane = tid & 63, wave = tid >> 6;
    const int m_lo = lane & 15, quad = lane >> 4;
    const int K0 = kt * KT;
    const int rowb = b * cSEQ;

    {
        const int r_in = lane >> 3;
        const int swz = ((lane & 7) ^ r_in) * 8;
        #pragma unroll
        for (int d = 0; d < 2; ++d) {
            int key = K0 + wave * 16 + d * 8 + r_in;
            int grow = rowb + min(key, cSEQ - 1);
            async16(qkv + (size_t)grow * (3 * cE) + cE + h * cDH + swz,
                    sK + (wave * 16 + d * 8) * cDH);
        }
    }
    for (int idx = tid; idx < KT * 32; idx += 384) {
        int key = idx >> 5, dp = idx & 31;
        int grow = rowb + min(K0 + key, cSEQ - 1);
        unsigned v = *(const unsigned*)(qkv + (size_t)grow * (3 * cE) + 2 * cE + h * cDH + dp * 2);
        sVT[(dp * 2) * 104 + key]     = ((const bf16*)&v)[0];
        sVT[(dp * 2 + 1) * 104 + key] = ((const bf16*)&v)[1];
    }
    bf16x8 qf[2][2];
    #pragma unroll
    for (int j = 0; j < 2; ++j)
        #pragma unroll
        for (int s = 0; s < 2; ++s) {
            int qrow = min(wave * 32 + j * 16 + m_lo, cSEQ - 1);
            qf[j][s] = *(const bf16x8*)(qkv + (size_t)(rowb + qrow) * (3 * cE)
                                        + h * cDH + s * 32 + quad * 8);
        }
    __syncthreads();

    f32x4 sc[2][6];
    #pragma unroll
    for (int j = 0; j < 2; ++j)
        #pragma unroll
        for (int t = 0; t < 6; ++t) {
            f32x4 z = {0.f, 0.f, 0.f, 0.f};
            sc[j][t] = z;
        }
    #pragma unroll
    for (int t = 0; t < 6; ++t)
        #pragma unroll
        for (int s2 = 0; s2 < 2; ++s2) {
            const int c = ((quad + s2 * 4) ^ (m_lo & 7)) * 8;
            bf16x8 kf = *(const bf16x8*)(sK + (t * 16 + m_lo) * cDH + c);
            #pragma unroll
            for (int j = 0; j < 2; ++j)
                sc[j][t] = __builtin_amdgcn_mfma_f32_16x16x32_bf16(qf[j][s2], kf, sc[j][t], 0, 0, 0);
        }

    bf16* sPw = sP + wave * (32 * 104);
    #pragma unroll
    for (int j = 0; j < 2; ++j) {
        float mr[4] = {-1e30f, -1e30f, -1e30f, -1e30f};
        #pragma unroll
        for (int t = 0; t < 6; ++t) {
            const bool pad = (K0 + t * 16 + m_lo) >= cSEQ;
            #pragma unroll
            for (int r = 0; r < 4; ++r) {
                float v = sc[j][t][r] * 0.125f;       // 1/sqrt(64)
                if (pad) v = -1e30f;
                sc[j][t][r] = v;
                mr[r] = fmaxf(mr[r], v);
            }
        }
        #pragma unroll
        for (int r = 0; r < 4; ++r) {
            mr[r] = fmaxf(mr[r], __shfl_xor(mr[r], 1));
            mr[r] = fmaxf(mr[r], __shfl_xor(mr[r], 2));
            mr[r] = fmaxf(mr[r], __shfl_xor(mr[r], 4));
            mr[r] = fmaxf(mr[r], __shfl_xor(mr[r], 8));
        }
        float lr[4] = {0.f, 0.f, 0.f, 0.f};
        #pragma unroll
        for (int t = 0; t < 6; ++t)
            #pragma unroll
            for (int r = 0; r < 4; ++r) {
                float p = __expf(sc[j][t][r] - mr[r]);
                lr[r] += p;
                sPw[(j * 16 + quad * 4 + r) * 104 + t * 16 + m_lo] = (bf16)p;
            }
        #pragma unroll
        for (int r = 0; r < 4; ++r) {
            lr[r] += __shfl_xor(lr[r], 1);
            lr[r] += __shfl_xor(lr[r], 2);
            lr[r] += __shfl_xor(lr[r], 4);
            lr[r] += __shfl_xor(lr[r], 8);
        }
        if (m_lo == 0) {
            #pragma unroll
            for (int r = 0; r < 4; ++r) {
                int qg = wave * 32 + j * 16 + quad * 4 + r;
                if (qg < cSEQ) {
                    int pi = ((b * cHEADS + h) * NJT + kt) * cSEQ + qg;
                    ml[pi * 2]     = mr[r];
                    ml[pi * 2 + 1] = lr[r];
                }
            }
        }
    }

    f32x4 oc[2][4];
    #pragma unroll
    for (int j = 0; j < 2; ++j)
        #pragma unroll
        for (int dt = 0; dt < 4; ++dt) {
            f32x4 z = {0.f, 0.f, 0.f, 0.f};
            oc[j][dt] = z;
        }
    #pragma unroll
    for (int s3 = 0; s3 < 3; ++s3) {
        bf16x8 pa[2], vf[4];
        #pragma unroll
        for (int j = 0; j < 2; ++j)
            pa[j] = *(const bf16x8*)(sPw + (j * 16 + m_lo) * 104 + s3 * 32 + quad * 8);
        #pragma unroll
        for (int dt = 0; dt < 4; ++dt)
            vf[dt] = *(const bf16x8*)(sVT + (dt * 16 + m_lo) * 104 + s3 * 32 + quad * 8);
        #pragma unroll
        for (int j = 0; j < 2; ++j)
            #pragma unroll
            for (int dt = 0; dt < 4; ++dt)
                oc[j][dt] = __builtin_amdgcn_mfma_f32_16x16x32_bf16(pa[j], vf[dt], oc[j][dt], 0, 0, 0);
    }

    #pragma unroll
    for (int j = 0; j < 2; ++j)
        #pragma unroll
        for (int dt = 0; dt < 4; ++dt)
            #pragma unroll
            for (int r = 0; r < 4; ++r) {
                int qg = wave * 32 + j * 16 + quad * 4 + r;
                if (qg < cSEQ) {
                    int pi = ((b * cHEADS + h) * NJT + kt) * cSEQ + qg;
                    op[(size_t)pi * cDH + dt * 16 + m_lo] = (bf16)oc[j][dt][r];
                }
            }
}

// ---------------- attention part 2: merge 2 key-half partials ----------------
__global__ __launch_bounds__(256) void attn_merge_kernel(
    const bf16* __restrict__ op, const float* __restrict__ ml,
    bf16* __restrict__ attn_o)
{
    int idx = blockIdx.x * 256 + threadIdx.x;   // over 192*169*8
    if (idx >= cB * cHEADS * cSEQ * 8) return;
    int d8 = idx & 7;
    int t  = idx >> 3;
    int q  = t % cSEQ;
    int bh = t / cSEQ;
    int b = bh / cHEADS, h = bh - b * cHEADS;
    const int pbase = (bh * NJT) * cSEQ + q;    // + jt*cSEQ per tile

    float ms[NJT], ls[NJT], mstar = -1e30f;
    #pragma unroll
    for (int j = 0; j < NJT; ++j) {
        ms[j] = ml[(pbase + j * cSEQ) * 2];
        ls[j] = ml[(pbase + j * cSEQ) * 2 + 1];
        mstar = fmaxf(mstar, ms[j]);
    }
    float den = 0.f, acc[8];
    #pragma unroll
    for (int u = 0; u < 8; ++u) acc[u] = 0.f;
    #pragma unroll
    for (int j = 0; j < NJT; ++j) {
        float w = __expf(ms[j] - mstar);
        den += w * ls[j];
        bf16x8 v = *(const bf16x8*)(op + (size_t)(pbase + j * cSEQ) * cDH + d8 * 8);
        #pragma unroll
        for (int u = 0; u < 8; ++u) acc[u] += w * (float)v[u];
    }
    float inv = 1.0f / den;
    bf16* outp = attn_o + ((size_t)(b * cSEQ + q)) * cE + h * cDH + d8 * 8;
    #pragma unroll
    for (int u = 0; u < 8; ++u) outp[u] = (bf16)(acc[u] * inv);
}

// ---------------- vis_mask: 2704 ones (read back as float32) ----------------
__global__ __launch_bounds__(256) void mask_kernel(float* __restrict__ out)
{
    int i = blockIdx.x * 256 + threadIdx.x;
    if (i < cN) out[i] = 1.0f;
}

// ---------------- host orchestration ----------------
extern "C" void kernel_launch(void* const* d_in, const int* in_sizes, int n_in,
                              void* d_out, int out_size, void* d_ws, size_t ws_size,
                              hipStream_t stream)
{
    const float* pixel   = (const float*)d_in[0];
    const float* patch_W = (const float*)d_in[1];
    const float* patch_b = (const float*)d_in[2];
    const float* row_emb = (const float*)d_in[3];
    const float* col_emb = (const float*)d_in[4];
    const float* cls     = (const float*)d_in[5];
    const float* ln1_g   = (const float*)d_in[6];
    const float* ln1_b   = (const float*)d_in[7];
    const float* in_w    = (const float*)d_in[8];
    const float* in_b    = (const float*)d_in[9];
    const float* out_w   = (const float*)d_in[10];
    const float* out_b   = (const float*)d_in[11];
    const float* ln2_g   = (const float*)d_in[12];
    const float* ln2_b   = (const float*)d_in[13];
    const float* mlp_w1  = (const float*)d_in[14];
    const float* mlp_b1  = (const float*)d_in[15];
    const float* mlp_w2  = (const float*)d_in[16];
    const float* mlp_b2  = (const float*)d_in[17];
    const float* fin_g   = (const float*)d_in[18];
    const float* fin_b   = (const float*)d_in[19];
    const float* br_w1   = (const float*)d_in[20];
    const float* br_b1   = (const float*)d_in[21];
    const float* br_w2   = (const float*)d_in[22];
    const float* br_b2   = (const float*)d_in[23];
    const float* br_g    = (const float*)d_in[24];
    const float* br_b    = (const float*)d_in[25];

    // workspace layout
    char* ws = (char*)d_ws;
    float* x      = (float*)(ws);                        // [2816,768] f32,  8,650,752
    bf16*  xn     = (bf16 *)(ws + 8650752);              // [2816,768] bf16, 4,325,376
    bf16*  qkv    = (bf16 *)(ws + 12976128);             // [2816,2304] bf16, 12,976,128
    bf16*  attn_o = (bf16 *)(ws + 25952256);             // [2816,768] bf16, 4,325,376
    bf16*  hmlp   = (bf16 *)(ws + 30277632);             // [2816,3072] bf16, 17,301,504
    bf16*  hb1    = (bf16 *)(ws + 47579136);             // [2816,1536] bf16, 8,650,752
    bf16*  wbuf   = (bf16 *)(ws + cWallBase);            // weight region (1 layer, or 12 in big mode)
    // aliases (disjoint lifetimes):
    float* pe     = (float*)(ws + 30277632);             // [2688,768] f32 (patch phase)
    bf16*  Apatch = (bf16 *)(ws + 47579136);             // [2688,768] bf16 (patch phase)
    bf16*  att_op = (bf16 *)(ws + 30277632);             // 8.3 MB used (attn phase, pre-MLP1)
    float* att_ml = (float*)(ws + 47579136);             // 519 KB used (attn phase, pre-branch)
    float* h2     = (float*)(ws + 12976128);             // [2816,2048] f32 (branch phase)

    const bool bigws = ws_size >= cWsNeedBig;            // 226 MB: all-layer weight residency

    auto conv = [&](const float* src, bf16* dst, int n) {
        int n4 = n / 4;
        f2b_kernel<<<(n4 + 255) / 256, 256, 0, stream>>>(src, dst, n4);
    };
    auto gemm64 = [&](const bf16* Abf, const bf16* Wbf, const float* bias,
                      const float* resid, float* oF, bf16* oB,
                      int M, int N, int K, int epi) {
        dim3 g(N / 64, M / 64);
        gemm_sq64_kernel<<<g, 256, 0, stream>>>(Abf, Wbf, bias, resid, oF, oB, M, N, K, epi);
    };
    auto gemm32 = [&](const bf16* Abf, const bf16* Wbf, const float* bias,
                      const float* resid, float* oF, bf16* oB,
                      int M, int N, int K, int epi) {
        dim3 g(N / 128, M / 128);
        gemm_bk32_kernel<<<g, 256, 0, stream>>>(Abf, Wbf, bias, resid, oF, oB, M, N, K, epi);
    };

    // ---- patch embed ----
    patchify_kernel<<<(cB * cNPAT * cE + 255) / 256, 256, 0, stream>>>(pixel, Apatch);
    conv(patch_W, wbuf, cE * cE);
    gemm64(Apatch, wbuf, patch_b, nullptr, pe, nullptr, cB * cNPAT, cE, cE, EPI_F32);
    assemble_kernel<<<(cN * cE + 255) / 256, 256, 0, stream>>>(pe, row_emb, col_emb, cls, x);

    // ---- weight conversion ----
    if (bigws) {
        // all 12 layers at once (overwrites patch wbuf, which is dead now)
        conv4_all_kernel<<<(cL * 1769472 + 255) / 256, 256, 0, stream>>>(
            in_w, out_w, mlp_w1, mlp_w2, wbuf);
    }

    const int merge_n = cB * cHEADS * cSEQ * 8;

    // ---- transformer layers ----
    for (int l = 0; l < cL; ++l) {
        bf16* wl = bigws ? (wbuf + (size_t)l * cWL) : wbuf;
        bf16* w_qkv = wl;
        bf16* w_out = wl + 1769472;
        bf16* w_m1  = wl + 2359296;
        bf16* w_m2  = wl + 4718592;
        if (!bigws) {
            conv4_kernel<<<(1769472 + 255) / 256, 256, 0, stream>>>(
                in_w  + (size_t)l * 3 * cE * cE,
                out_w + (size_t)l * cE * cE,
                mlp_w1 + (size_t)l * cMLP * cE,
                mlp_w2 + (size_t)l * cE * cMLP, wbuf);
        }
        ln_kernel<<<cN, 256, 0, stream>>>(x, ln1_g + l * cE, ln1_b + l * cE, xn, nullptr, cE);
        gemm32(xn, w_qkv, in_b + (size_t)l * 3 * cE, nullptr, nullptr, qkv, cMp, 3 * cE, cE, EPI_BF16);
        attn_mfma_kernel<<<dim3(cHEADS, cB, NJT), 384, 0, stream>>>(qkv, att_op, att_ml);
        attn_merge_kernel<<<(merge_n + 255) / 256, 256, 0, stream>>>(att_op, att_ml, attn_o);
        gemm64(attn_o, w_out, out_b + (size_t)l * cE, x, x, nullptr, cMp, cE, cE, EPI_RES);
        ln_kernel<<<cN, 256, 0, stream>>>(x, ln2_g + l * cE, ln2_b + l * cE, xn, nullptr, cE);
        gemm32(xn, w_m1, mlp_b1 + (size_t)l * cMLP, nullptr, nullptr, hmlp, cMp, cMLP, cE, EPI_GELU_BF16);
        gemm64(hmlp, w_m2, mlp_b2 + (size_t)l * cE, x, x, nullptr, cMp, cE, cMLP, EPI_RES);
    }

    // ---- final LN + branch head ----
    ln_kernel<<<cN, 256, 0, stream>>>(x, fin_g, fin_b, xn, nullptr, cE);
    conv(br_w1, wbuf, 2 * cE * cE);
    conv(br_w2, wbuf + 1179648, cOUT * 2 * cE);
    gemm32(xn, wbuf, br_b1, nullptr, nullptr, hb1, cMp, 2 * cE, cE, EPI_GELU_BF16);
    gemm32(hb1, wbuf + 1179648, br_b2, nullptr, h2, nullptr, cMp, cOUT, 2 * cE, EPI_F32);
    ln_kernel<<<cN, 256, 0, stream>>>(h2, br_g, br_b, nullptr, (float*)d_out, cOUT);

    // ---- vis_mask ----
    mask_kernel<<<(cN + 255) / 256, 256, 0, stream>>>((float*)d_out + (size_t)cN * cOUT);
}